// Round 5
// baseline (1655.733 us; speedup 1.0000x reference)
//
#include <hip/hip_runtime.h>
#include <hip/hip_cooperative_groups.h>

namespace cg = cooperative_groups;

#define B_SZ 256
#define F_SZ 4
#define M_SZ 256
#define D_SZ 8192
#define NITER 10

typedef signed char i8;
typedef unsigned long long u64;
typedef signed char c16 __attribute__((ext_vector_type(16)));
typedef int v4i __attribute__((ext_vector_type(4)));

#define NBFM (B_SZ * F_SZ * M_SZ)   // 262144

// ---- workspace layout (bytes) ----
#define OFF_CB    ((size_t)0)          // i8  [F][M][D]      8 MB
#define OFF_CBF   ((size_t)8  << 20)   // i8  frag-linear B  8 MB: [f][dt64][ks8][dsub8][lane64][8]
#define OFF_IN8   ((size_t)16 << 20)   // i8  [B][D]         2 MB
#define OFF_CBBT  ((size_t)18 << 20)   // u64 [F][128][M]    1 MB
#define OFF_INB   ((size_t)19 << 20)   // u64 [B][128]       256 KB
#define OFF_ESB   ((size_t)20 << 20)   // u64 [B][F][128]    1 MB  (sign bits)
#define OFF_EZB   ((size_t)21 << 20)   // u64 [B][F][128]    1 MB  (zero bits)
#define OFF_AF01  ((size_t)22 << 20)   // i8  frag-linear A planes 0,1  512 KB
#define OFF_AF2   (OFF_AF01 + ((size_t)512 << 10))   // i8 frag-linear A plane 2, 256 KB
#define OFF_P1    ((size_t)23 << 20)   // i32 [24][B*F*M]    24 MB  (iter1 partials)
#define OFF_S32   ((size_t)48 << 20)   // i32 [F][D]         128 KB
#define OFF_PDIG  (OFF_S32 + (size_t)F_SZ * D_SZ * 4)   // i8 [3][F][D] 96 KB
#define OFF_CHG   (OFF_PDIG + (size_t)3 * F_SZ * D_SZ)  // int[16]

// frag-linear A slot index for (f, b, m)
__device__ __forceinline__ size_t afslot(int f, int b, int m) {
  return (size_t)(((f * 4 + (b >> 6)) * 8 + (m >> 5)) * 4 + ((b >> 4) & 3)) * 64
         + ((m >> 3) & 3) * 16 + (b & 15);
}

// ---------------- converts / init ----------------

__global__ __launch_bounds__(256) void k_cvt_cb(const float* __restrict__ src,
                                                i8* __restrict__ cb, i8* __restrict__ cbF) {
  __shared__ i8 tile[32][33];   // [m][d]
  const int bid = blockIdx.x;           // 8192 = 4f * 8mt * 256dt
  const int f = bid >> 11;
  const int rem = bid & 2047;
  const int m0 = (rem >> 8) << 5;
  const int d0 = (rem & 255) << 5;
  const int t = threadIdx.x;
  const int i = t >> 3, j = (t & 7) << 2;
  const float4 v = *(const float4*)(src + ((size_t)(f * M_SZ + m0 + i)) * D_SZ + d0 + j);
  char4 c;
  c.x = v.x > 0.f ? 1 : -1;
  c.y = v.y > 0.f ? 1 : -1;
  c.z = v.z > 0.f ? 1 : -1;
  c.w = v.w > 0.f ? 1 : -1;
  *(char4*)(cb + ((size_t)(f * M_SZ + m0 + i)) * D_SZ + d0 + j) = c;
  tile[i][j + 0] = c.x; tile[i][j + 1] = c.y; tile[i][j + 2] = c.z; tile[i][j + 3] = c.w;
  __syncthreads();
  if (t < 128) {
    const int mg = t >> 5;       // 8-m group within the 32-m tile
    const int dd = t & 31;
    const int d = d0 + dd;
    const int dt = d >> 7, dsub = (d >> 4) & 7, dlo = d & 15;
    const int ks = m0 >> 5;
    u64 w = 0;
    #pragma unroll
    for (int jj = 0; jj < 8; ++jj)
      w |= ((u64)(unsigned char)tile[mg * 8 + jj][dd]) << (8 * jj);
    *(u64*)&cbF[((size_t)((((f * 64 + dt) * 8 + ks) * 8 + dsub) * 64 + mg * 16 + dlo)) * 8] = w;
  }
}

__global__ __launch_bounds__(256) void k_cvt_in(const float* __restrict__ src, i8* __restrict__ dst) {
  const int idx = blockIdx.x * 256 + threadIdx.x;   // 524288 float4s
  const float4 v = ((const float4*)src)[idx];
  char4 c;
  c.x = v.x > 0.f ? 1 : -1;
  c.y = v.y > 0.f ? 1 : -1;
  c.z = v.z > 0.f ? 1 : -1;
  c.w = v.w > 0.f ? 1 : -1;
  ((char4*)dst)[idx] = c;
}

__global__ __launch_bounds__(256) void k_pack_cb(const i8* __restrict__ cb, u64* __restrict__ cbbT) {
  const int id = blockIdx.x * 256 + threadIdx.x;   // 131072 = f*32768 + w*256 + m
  const int f = id >> 15;
  const int rem = id & 32767;
  const int w = rem >> 8;
  const int m = rem & 255;
  const i8* src = cb + ((size_t)(f * M_SZ + m)) * D_SZ + w * 64;
  u64 r = 0;
  #pragma unroll
  for (int k = 0; k < 4; ++k) {
    c16 v = *(const c16*)(src + k * 16);
    u64 part = 0;
    #pragma unroll
    for (int j = 0; j < 16; ++j) part |= ((u64)(((unsigned char)v[j]) >> 7)) << j;
    r |= part << (k * 16);
  }
  cbbT[((size_t)(f * 128 + w)) * 256 + m] = r;
}

__global__ __launch_bounds__(256) void k_pack_in(const i8* __restrict__ in8, u64* __restrict__ inb) {
  const int id = blockIdx.x * 256 + threadIdx.x;   // 32768 = b*128 + w
  const int b = id >> 7;
  const int w = id & 127;
  const i8* src = in8 + (size_t)b * D_SZ + w * 64;
  u64 r = 0;
  #pragma unroll
  for (int k = 0; k < 4; ++k) {
    c16 v = *(const c16*)(src + k * 16);
    u64 part = 0;
    #pragma unroll
    for (int j = 0; j < 16; ++j) part |= ((u64)(((unsigned char)v[j]) >> 7)) << j;
    r |= part << (k * 16);
  }
  inb[(size_t)b * 128 + w] = r;
}

__global__ __launch_bounds__(256) void k_S(const i8* __restrict__ cb, int* __restrict__ S) {
  const int id = blockIdx.x * 256 + threadIdx.x;    // 32768 = [f][d]
  const int f = id >> 13, d = id & 8191;
  const i8* p = cb + (size_t)f * M_SZ * D_SZ + d;
  int s = 0;
  for (int m = 0; m < M_SZ; ++m) s += p[(size_t)m * D_SZ];
  S[id] = s;
}

// P' = P/8 (exact), 3 radix-255 signed digits in [-127,127]
__global__ __launch_bounds__(256) void k_P(const int* __restrict__ S, i8* __restrict__ pdig) {
  const int d = blockIdx.x * 256 + threadIdx.x;     // 8192
  const int s0 = S[d], s1 = S[D_SZ + d], s2 = S[2 * D_SZ + d], s3 = S[3 * D_SZ + d];
  int P[4];
  P[0] = s1 * s2 * s3;
  P[1] = s0 * s2 * s3;
  P[2] = s0 * s1 * s3;
  P[3] = s0 * s1 * s2;
  for (int f = 0; f < 4; ++f) {
    int x = P[f] >> 3;
    #pragma unroll
    for (int p = 0; p < 2; ++p) {
      const int y = x + 127;
      const int q = (y >= 0) ? (y / 255) : -((-y + 254) / 255);
      const int dg = x - q * 255;
      pdig[((size_t)(p * F_SZ + f)) * D_SZ + d] = (i8)dg;
      x = q;
    }
    pdig[((size_t)(2 * F_SZ + f)) * D_SZ + d] = (i8)x;
  }
}

// ---------------- iteration-1 stage A (MFMA, 3 digit planes of P/8) ----------------

__global__ __launch_bounds__(256) void ga2_kernel(
    const i8* __restrict__ in8, const i8* __restrict__ cb,
    const i8* __restrict__ pdig, int* __restrict__ p1)
{
  __shared__ __align__(16) i8 lA[64 * 48];
  __shared__ __align__(16) i8 lB[128 * 48];

  const int bid = blockIdx.x;
  const int s = bid & 7;
  const int r = bid >> 3;
  const int p = r % 3;
  const int q = r / 3;
  const int f = q & 3;
  const int ct = q >> 2;
  const int b0 = (ct >> 1) * 64;
  const int m0 = (ct & 1) * 128;
  const int ksteps = 32;
  const int kbase = s << 10;

  const int t = threadIdx.x;
  const int lane = t & 63;
  const int wv = t >> 6;
  const int wrow = (wv >> 1) * 32;
  const int wcol = (wv & 1) * 64;

  const int arow = t >> 1;
  const int aoff = (t & 1) * 16;
  const i8* pB  = cb   + ((size_t)(f * M_SZ + m0 + arow)) * D_SZ + aoff;
  const i8* pDg = pdig + ((size_t)(p * F_SZ + f)) * D_SZ + aoff;
  const i8* pIn = in8  + (size_t)(b0 + arow) * D_SZ + aoff;

  v4i acc[2][4];
  #pragma unroll
  for (int tr = 0; tr < 2; ++tr)
    #pragma unroll
    for (int tc = 0; tc < 4; ++tc) acc[tr][tc] = 0;

  c16 va = 0, vb = 0;
  {
    const int kk = kbase;
    vb = (*(const c16*)(pB + kk)) * (*(const c16*)(pDg + kk));
    if (t < 128) va = *(const c16*)(pIn + kk);
  }

  for (int j = 0; j < ksteps; ++j) {
    c16 sa = va, sb = vb;
    if (j + 1 < ksteps) {
      const int kk = kbase + (j + 1) * 32;
      vb = (*(const c16*)(pB + kk)) * (*(const c16*)(pDg + kk));
      if (t < 128) va = *(const c16*)(pIn + kk);
    }
    __syncthreads();
    if (t < 128) *(c16*)&lA[arow * 48 + aoff] = sa;
    *(c16*)&lB[arow * 48 + aoff] = sb;
    __syncthreads();

    const int rsel = lane & 15;
    const int kq = (lane >> 4) * 8;
    long af[2], bf[4];
    #pragma unroll
    for (int tr = 0; tr < 2; ++tr) af[tr] = *(const long*)&lA[(wrow + tr * 16 + rsel) * 48 + kq];
    #pragma unroll
    for (int tc = 0; tc < 4; ++tc) bf[tc] = *(const long*)&lB[(wcol + tc * 16 + rsel) * 48 + kq];
    #pragma unroll
    for (int tr = 0; tr < 2; ++tr)
      #pragma unroll
      for (int tc = 0; tc < 4; ++tc)
        acc[tr][tc] = __builtin_amdgcn_mfma_i32_16x16x32_i8(af[tr], bf[tc], acc[tr][tc], 0, 0, 0);
  }

  const int colb = lane & 15;
  const int rowq = (lane >> 4) * 4;
  const size_t obase = (size_t)(p * 8 + s) * NBFM;
  #pragma unroll
  for (int tr = 0; tr < 2; ++tr)
    #pragma unroll
    for (int tc = 0; tc < 4; ++tc)
      #pragma unroll
      for (int rr = 0; rr < 4; ++rr) {
        const int b = b0 + wrow + tr * 16 + rowq + rr;
        const int m = m0 + wcol + tc * 16 + colb;
        p1[obase + (((size_t)(b * F_SZ + f)) << 8) + m] = acc[tr][tc][rr];
      }
}

// recombine 24 slices -> 3 radix-256 digits, frag-linear
__global__ __launch_bounds__(256) void k_digits1(const int* __restrict__ p1,
                                                 i8* __restrict__ aF01, i8* __restrict__ aF2) {
  const int idx = blockIdx.x * 256 + threadIdx.x;
  long long g[3];
  #pragma unroll
  for (int p = 0; p < 3; ++p) {
    long long gg = 0;
    #pragma unroll
    for (int s = 0; s < 8; ++s) gg += (long long)p1[(size_t)(p * 8 + s) * NBFM + idx];
    g[p] = gg;
  }
  const long long sim = g[0] + 255LL * g[1] + 65025LL * g[2];
  int x = (int)sim;
  const int r1 = (x + 128) >> 8;
  const int d0 = x - (r1 << 8);
  const int r2 = (r1 + 128) >> 8;
  const int d1 = r1 - (r2 << 8);
  const int bf = idx >> 8;        // b*4+f
  const int m = idx & 255;
  const int b = bf >> 2, f = bf & 3;
  const size_t sl = afslot(f, b, m);
  const int by = m & 7;
  aF01[sl * 16 + by] = (i8)d0;
  aF01[sl * 16 + 8 + by] = (i8)d1;
  aF2[sl * 8 + by] = (i8)r2;
}

// ---------------- shared gb tile compute (B from generic pointer: LDS or global) ----------------

template<int NP, bool FIRST>
__device__ __forceinline__ bool gb_half(
    const i8* bsrc, const i8* aF01, const i8* aF2,
    u64* esb, u64* ezb, const int* S32,
    int f, int bt, int d0, int t)
{
  const int lane = t & 63;
  const int wv = t >> 6;
  const int wrow = (wv >> 1) * 32;
  const int wcol = (wv & 1) * 64;
  const int tb = wcol >> 4;
  const int sub0 = wrow >> 4;
  const int b0 = bt * 64;

  v4i acc[NP][2][4];
  #pragma unroll
  for (int pp = 0; pp < NP; ++pp)
    #pragma unroll
    for (int tr = 0; tr < 2; ++tr)
      #pragma unroll
      for (int tc = 0; tc < 4; ++tc) acc[pp][tr][tc] = 0;

  const i8* pA = aF01 + ((size_t)(f * 4 + bt)) * 32768;
  const i8* pA2 = aF2 + ((size_t)(f * 4 + bt)) * 16384;

  #pragma unroll
  for (int ks = 0; ks < 8; ++ks) {
    long bf[4];
    #pragma unroll
    for (int tc = 0; tc < 4; ++tc)
      bf[tc] = *(const long*)&bsrc[(((ks * 8 + tb + tc) * 64 + lane)) * 8];
    long af[NP][2];
    #pragma unroll
    for (int tr = 0; tr < 2; ++tr) {
      union { c16 v; long l[2]; } x;
      x.v = *(const c16*)(pA + ((size_t)((ks * 4 + sub0 + tr) * 64 + lane)) * 16);
      af[0][tr] = x.l[0];
      af[1][tr] = x.l[1];
      if (NP > 2) af[2][tr] = *(const long*)(pA2 + ((size_t)((ks * 4 + sub0 + tr) * 64 + lane)) * 8);
    }
    #pragma unroll
    for (int pp = 0; pp < NP; ++pp)
      #pragma unroll
      for (int tr = 0; tr < 2; ++tr)
        #pragma unroll
        for (int tc = 0; tc < 4; ++tc)
          acc[pp][tr][tc] = __builtin_amdgcn_mfma_i32_16x16x32_i8(af[pp][tr], bf[tc], acc[pp][tr][tc], 0, 0, 0);
  }

  bool chl = false;
  const int colb = lane & 15;

  #pragma unroll
  for (int tr = 0; tr < 2; ++tr) {
    unsigned long long bs[4][4], bz[4][4];
    #pragma unroll
    for (int rr = 0; rr < 4; ++rr)
      #pragma unroll
      for (int tc = 0; tc < 4; ++tc) {
        int o = acc[0][tr][tc][rr];
        if (NP > 1) o += acc[1][tr][tc][rr] * 256;
        if (NP > 2) o += acc[2][tr][tc][rr] * 65536;
        bs[rr][tc] = __ballot(o < 0);
        bz[rr][tc] = __ballot(o == 0);
        if (FIRST) {
          const int sg = (o > 0) - (o < 0);
          const int d = d0 + wcol + tc * 16 + colb;
          chl |= (sg != S32[f * D_SZ + d]);
        }
      }
    u64 ws = 0, wz = 0;
    #pragma unroll
    for (int rl = 0; rl < 16; ++rl) {
      const int g = rl >> 2, rr = rl & 3;
      u64 vs = 0, vz = 0;
      #pragma unroll
      for (int tc = 0; tc < 4; ++tc) {
        vs |= ((bs[rr][tc] >> (g * 16)) & 0xFFFFull) << (tc * 16);
        vz |= ((bz[rr][tc] >> (g * 16)) & 0xFFFFull) << (tc * 16);
      }
      if (lane == rl) { ws = vs; wz = vz; }
    }
    if (lane < 16) {
      const int row = b0 + wrow + tr * 16 + lane;
      const size_t wi = ((size_t)(row * 4 + f)) * 128 + ((d0 + wcol) >> 6);
      if (!FIRST) chl |= (ws != esb[wi]) | (wz != ezb[wi]);
      esb[wi] = ws;
      ezb[wi] = wz;
    }
  }
  return chl;
}

// ---------------- fused persistent loop kernel (cooperative) ----------------
// 512 blocks x 256 threads. LDS = 32 KB (one cbF slice) + 4 KB AL = 36,864 B (< 64 KB).
// Second cbF slice read direct from global (L2-resident within the persistent kernel).

__global__ __launch_bounds__(256, 2) void k_loop(
    i8* aF01, const i8* __restrict__ aF2, const i8* __restrict__ cbF,
    const u64* __restrict__ cbbT, const u64* __restrict__ inb,
    u64* esb, u64* ezb, const int* __restrict__ S32,
    int* chg, int* __restrict__ out)
{
  __shared__ __align__(16) i8 lB[32768];
  __shared__ __align__(16) u64 AL[128][4];

  const int bid = blockIdx.x;
  const int t = threadIdx.x;
  const int f = bid & 3;
  const int bt = (bid >> 2) & 3;
  const int dthi = bid >> 4;          // 0..31
  const int bp = bid >> 2;            // 0..127

  // ---- stage slice dthi into LDS (persists all iterations) ----
  {
    const i8* src = cbF + ((size_t)(f * 64 + dthi)) * 32768;
    #pragma unroll
    for (int i = 0; i < 8; ++i) {
      const int off = i * 4096 + t * 16;
      *(c16*)&lB[off] = *(const c16*)(src + off);
    }
  }
  const i8* gB = cbF + ((size_t)(f * 64 + dthi + 32)) * 32768;
  __syncthreads();

  cg::grid_group grid = cg::this_grid();

  // ---- iteration 1: gb only (NP=3, FIRST) ----
  {
    bool chl = gb_half<3, true>(lB, aF01, aF2, esb, ezb, S32, f, bt, dthi * 128, t);
    chl |= gb_half<3, true>(gB, aF01, aF2, esb, ezb, S32, f, bt, (dthi + 32) * 128, t);
    if (__any(chl)) { if ((t & 63) == 0) atomicOr(&chg[1], 1); }
  }
  grid.sync();

  for (int it = 2; it <= NITER; ++it) {
    if (__hip_atomic_load(&chg[it - 1], __ATOMIC_RELAXED, __HIP_MEMORY_SCOPE_AGENT) == 0)
      break;   // uniform across grid (chg finalized before last sync)

    // ---- ga: bitwise sim for rows 2bp, 2bp+1 -> aF01 digits ----
    {
      const int r = t >> 7, w = t & 127;
      const int b = bp * 2 + r;
      int ffs[3]; int c = 0;
      for (int ff = 0; ff < 4; ++ff) if (ff != f) ffs[c++] = ff;
      const size_t base = (size_t)b * 512;
      const u64 s = inb[(size_t)b * 128 + w]
        ^ esb[base + ffs[0] * 128 + w] ^ esb[base + ffs[1] * 128 + w] ^ esb[base + ffs[2] * 128 + w];
      const u64 nz = ~(ezb[base + ffs[0] * 128 + w] | ezb[base + ffs[1] * 128 + w] | ezb[base + ffs[2] * 128 + w]);
      AL[w][r * 2] = s;
      AL[w][r * 2 + 1] = nz;
    }
    __syncthreads();
    {
      const int m = t;
      int a0 = 0, a1 = 0, c0 = 0, c1 = 0;
      const u64* pc = cbbT + (size_t)f * 32768 + m;
      #pragma unroll 4
      for (int w = 0; w < 128; ++w) {
        const u64 cbw = pc[w * 256];
        const u64 s0 = AL[w][0], z0 = AL[w][1], s1 = AL[w][2], z1 = AL[w][3];
        a0 += (int)__popcll((s0 ^ cbw) & z0);
        a1 += (int)__popcll((s1 ^ cbw) & z1);
        c0 += (int)__popcll(z0);
        c1 += (int)__popcll(z1);
      }
      const int sim0 = c0 - 2 * a0;
      const int sim1 = c1 - 2 * a1;
      const int by = m & 7;
      int d1 = (sim0 + 128) >> 8; int d0v = sim0 - (d1 << 8);
      size_t sl = afslot(f, bp * 2, m);
      aF01[sl * 16 + by] = (i8)d0v; aF01[sl * 16 + 8 + by] = (i8)d1;
      d1 = (sim1 + 128) >> 8; d0v = sim1 - (d1 << 8);
      sl = afslot(f, bp * 2 + 1, m);
      aF01[sl * 16 + by] = (i8)d0v; aF01[sl * 16 + 8 + by] = (i8)d1;
    }
    __syncthreads();
    grid.sync();

    // ---- gb: NP=2 GEMM on both owned slices ----
    {
      bool chl = gb_half<2, false>(lB, aF01, aF2, esb, ezb, S32, f, bt, dthi * 128, t);
      chl |= gb_half<2, false>(gB, aF01, aF2, esb, ezb, S32, f, bt, (dthi + 32) * 128, t);
      if (__any(chl)) { if ((t & 63) == 0) atomicOr(&chg[it], 1); }
    }
    grid.sync();
  }

  // ---- final: sim + argmax for rows 2bp, 2bp+1 ----
  {
    const int r = t >> 7, w = t & 127;
    const int b = bp * 2 + r;
    const size_t a = ((size_t)b * 4 + f) * 128 + w;
    AL[w][r * 2] = esb[a];
    AL[w][r * 2 + 1] = ~ezb[a];
  }
  __syncthreads();
  long long best0, best1;
  {
    const int m = t;
    int a0 = 0, a1 = 0, c0 = 0, c1 = 0;
    const u64* pc = cbbT + (size_t)f * 32768 + m;
    #pragma unroll 4
    for (int w = 0; w < 128; ++w) {
      const u64 cbw = pc[w * 256];
      const u64 s0 = AL[w][0], z0 = AL[w][1], s1 = AL[w][2], z1 = AL[w][3];
      a0 += (int)__popcll((s0 ^ cbw) & z0);
      a1 += (int)__popcll((s1 ^ cbw) & z1);
      c0 += (int)__popcll(z0);
      c1 += (int)__popcll(z1);
    }
    const int sim0 = c0 - 2 * a0;
    const int sim1 = c1 - 2 * a1;
    best0 = ((long long)sim0 << 32) | (long long)(unsigned)(255 - m);
    best1 = ((long long)sim1 << 32) | (long long)(unsigned)(255 - m);
  }
  __syncthreads();
  long long* red = (long long*)&AL[0][0];   // 4 KB overlay (AL dead now)
  red[t] = best0;
  red[256 + t] = best1;
  __syncthreads();
  for (int s2 = 128; s2 > 0; s2 >>= 1) {
    if (t < s2) {
      if (red[t + s2] > red[t]) red[t] = red[t + s2];
      if (red[256 + t + s2] > red[256 + t]) red[256 + t] = red[256 + t + s2];
    }
    __syncthreads();
  }
  if (t == 0) {
    out[(bp * 2) * 4 + f] = 255 - (int)(red[0] & 0xFFFF);
    out[(bp * 2 + 1) * 4 + f] = 255 - (int)(red[256] & 0xFFFF);
    if (bid == 0) {
      int k = NITER;
      for (int i = 1; i <= NITER; ++i) if (chg[i] == 0) { k = i; break; }
      out[B_SZ * F_SZ] = k;
    }
  }
}

// ---------------- fallback (round-3 verified) kernels ----------------

template<int NP, bool FIRST>
__device__ __forceinline__ void gb_body(
    const i8* __restrict__ aF01, const i8* __restrict__ aF2,
    const i8* __restrict__ cbF,
    u64* __restrict__ esb, u64* __restrict__ ezb,
    const int* __restrict__ S32,
    int* __restrict__ changed, int it)
{
  __shared__ __align__(16) i8 lB[32768];

  if (!FIRST) { if (changed[it - 1] == 0) return; }

  const int bid = blockIdx.x;
  const int f = bid & 3;
  const int r = bid >> 2;
  const int bt = r & 3;
  const int dt = r >> 2;

  const int t = threadIdx.x;
  {
    const i8* src = cbF + ((size_t)(f * 64 + dt)) * 32768;
    #pragma unroll
    for (int i = 0; i < 8; ++i) {
      const int off = i * 4096 + t * 16;
      *(c16*)&lB[off] = *(const c16*)(src + off);
    }
  }
  __syncthreads();

  bool chl = gb_half<NP, FIRST>(lB, aF01, aF2, esb, ezb, S32, f, bt, dt * 128, t);
  if (__any(chl)) { if ((t & 63) == 0) atomicOr(&changed[it], 1); }
}

__global__ __launch_bounds__(256, 4) void gb_loop_k(
    const i8* __restrict__ aF01, const i8* __restrict__ cbF,
    u64* __restrict__ esb, u64* __restrict__ ezb,
    int* __restrict__ changed, int it)
{
  gb_body<2, false>(aF01, nullptr, cbF, esb, ezb, nullptr, changed, it);
}

__global__ __launch_bounds__(256, 2) void gb_first_k(
    const i8* __restrict__ aF01, const i8* __restrict__ aF2, const i8* __restrict__ cbF,
    u64* __restrict__ esb, u64* __restrict__ ezb,
    const int* __restrict__ S32, int* __restrict__ changed, int it)
{
  gb_body<3, true>(aF01, aF2, cbF, esb, ezb, S32, changed, it);
}

__global__ __launch_bounds__(512) void ga_bit(
    const u64* __restrict__ esb, const u64* __restrict__ ezb,
    const u64* __restrict__ inb, const u64* __restrict__ cbbT,
    i8* __restrict__ aF01, const int* __restrict__ changed, int it)
{
  __shared__ u64 AL[128][4];

  if (changed[it - 1] == 0) return;

  const int bid = blockIdx.x;
  const int f = bid & 3;
  const int b0 = (bid >> 2) * 2;
  const int t = threadIdx.x;

  if (t < 256) {
    const int r = t >> 7, w = t & 127;
    const int b = b0 + r;
    int ffs[3]; int c = 0;
    for (int ff = 0; ff < 4; ++ff) if (ff != f) ffs[c++] = ff;
    const size_t base = (size_t)b * 512;
    const u64 s = inb[(size_t)b * 128 + w]
      ^ esb[base + ffs[0] * 128 + w] ^ esb[base + ffs[1] * 128 + w] ^ esb[base + ffs[2] * 128 + w];
    const u64 nz = ~(ezb[base + ffs[0] * 128 + w] | ezb[base + ffs[1] * 128 + w] | ezb[base + ffs[2] * 128 + w]);
    AL[w][r * 2] = s;
    AL[w][r * 2 + 1] = nz;
  }
  __syncthreads();

  const int r = t >> 8;
  const int m = t & 255;
  int a = 0, c = 0;
  const u64* pc = cbbT + (size_t)f * 32768 + m;
  #pragma unroll 4
  for (int w = 0; w < 128; ++w) {
    const u64 cbw = pc[w * 256];
    a += (int)__popcll((AL[w][r * 2] ^ cbw) & AL[w][r * 2 + 1]);
    c += (int)__popcll(AL[w][r * 2 + 1]);
  }
  const int sim = c - 2 * a;

  const int d1 = (sim + 128) >> 8;
  const int d0v = sim - (d1 << 8);
  const int b = b0 + r;
  const size_t sl = afslot(f, b, m);
  const int by = m & 7;
  aF01[sl * 16 + by] = (i8)d0v;
  aF01[sl * 16 + 8 + by] = (i8)d1;
}

__global__ __launch_bounds__(512) void k_final(
    const u64* __restrict__ esb, const u64* __restrict__ ezb,
    const u64* __restrict__ cbbT, const int* __restrict__ chg,
    int* __restrict__ out)
{
  __shared__ u64 AL[128][4];
  __shared__ long long red[2][256];

  const int bid = blockIdx.x;
  const int f = bid & 3;
  const int b0 = (bid >> 2) * 2;
  const int t = threadIdx.x;

  if (t < 256) {
    const int r = t >> 7, w = t & 127;
    const int b = b0 + r;
    const size_t a = ((size_t)b * 4 + f) * 128 + w;
    AL[w][r * 2] = esb[a];
    AL[w][r * 2 + 1] = ~ezb[a];
  }
  __syncthreads();

  const int r = t >> 8;
  const int m = t & 255;
  int a = 0, c = 0;
  const u64* pc = cbbT + (size_t)f * 32768 + m;
  #pragma unroll 4
  for (int w = 0; w < 128; ++w) {
    const u64 cbw = pc[w * 256];
    a += (int)__popcll((AL[w][r * 2] ^ cbw) & AL[w][r * 2 + 1]);
    c += (int)__popcll(AL[w][r * 2 + 1]);
  }
  const int sim = c - 2 * a;

  red[r][m] = ((long long)sim << 32) | (long long)(unsigned)(255 - m);
  __syncthreads();
  for (int s2 = 128; s2 > 0; s2 >>= 1) {
    if (m < s2) {
      if (red[r][m + s2] > red[r][m]) red[r][m] = red[r][m + s2];
    }
    __syncthreads();
  }
  if (m == 0) {
    out[(b0 + r) * 4 + f] = 255 - (int)(red[r][0] & 0xFFFF);
    if (t == 0 && bid == 0) {
      int k = NITER;
      for (int i = 1; i <= NITER; ++i) if (chg[i] == 0) { k = i; break; }
      out[B_SZ * F_SZ] = k;
    }
  }
}

// ---------------- host ----------------

extern "C" void kernel_launch(void* const* d_in, const int* in_sizes, int n_in,
                              void* d_out, int out_size, void* d_ws, size_t ws_size,
                              hipStream_t stream) {
  const float* f_in = (const float*)d_in[0];   // [B][D]
  const float* f_cb = (const float*)d_in[1];   // [F][M][D]
  int* out = (int*)d_out;
  char* ws = (char*)d_ws;

  i8*  cb8  = (i8*)(ws + OFF_CB);
  i8*  cbF  = (i8*)(ws + OFF_CBF);
  i8*  in8  = (i8*)(ws + OFF_IN8);
  u64* cbbT = (u64*)(ws + OFF_CBBT);
  u64* inb  = (u64*)(ws + OFF_INB);
  u64* esb  = (u64*)(ws + OFF_ESB);
  u64* ezb  = (u64*)(ws + OFF_EZB);
  i8*  aF01 = (i8*)(ws + OFF_AF01);
  i8*  aF2  = (i8*)(ws + OFF_AF2);
  int* p1   = (int*)(ws + OFF_P1);
  int* S32  = (int*)(ws + OFF_S32);
  i8*  pdig = (i8*)(ws + OFF_PDIG);
  int* chg  = (int*)(ws + OFF_CHG);

  hipMemsetAsync(chg, 0, 64, stream);
  k_cvt_cb<<<dim3(8192), dim3(256), 0, stream>>>(f_cb, cb8, cbF);
  k_cvt_in<<<dim3(2048), dim3(256), 0, stream>>>(f_in, in8);
  k_pack_cb<<<dim3(512), dim3(256), 0, stream>>>(cb8, cbbT);
  k_pack_in<<<dim3(128), dim3(256), 0, stream>>>(in8, inb);
  k_S<<<dim3(128), dim3(256), 0, stream>>>(cb8, S32);
  k_P<<<dim3(32), dim3(256), 0, stream>>>(S32, pdig);

  // iteration 1 stage A (big-integer est0 via P/8 digit planes, MFMA)
  ga2_kernel<<<dim3(768), dim3(256), 0, stream>>>(in8, cb8, pdig, p1);
  k_digits1<<<dim3(1024), dim3(256), 0, stream>>>(p1, aF01, aF2);

  // fused persistent loop: it=1 gb + (ga,gb) x it=2..10 + final argmax
  void* args[] = { (void*)&aF01, (void*)&aF2, (void*)&cbF, (void*)&cbbT, (void*)&inb,
                   (void*)&esb, (void*)&ezb, (void*)&S32, (void*)&chg, (void*)&out };
  hipError_t cerr = hipLaunchCooperativeKernel((void*)k_loop, dim3(512), dim3(256),
                                               args, 0, stream);
  if (cerr != hipSuccess) {
    // fallback: verified multi-kernel path (round-3 structure)
    gb_first_k<<<dim3(1024), dim3(256), 0, stream>>>(aF01, aF2, cbF, esb, ezb, S32, chg, 1);
    for (int it = 2; it <= NITER; ++it) {
      ga_bit<<<dim3(512), dim3(512), 0, stream>>>(esb, ezb, inb, cbbT, aF01, chg, it);
      gb_loop_k<<<dim3(1024), dim3(256), 0, stream>>>(aF01, cbF, esb, ezb, chg, it);
    }
    k_final<<<dim3(512), dim3(512), 0, stream>>>(esb, ezb, cbbT, chg, out);
  }
}

// Round 6
// 876.163 us; speedup vs baseline: 1.8898x; 1.8898x over previous
//
#include <hip/hip_runtime.h>

#define B_SZ 256
#define F_SZ 4
#define M_SZ 256
#define D_SZ 8192
#define NITER 10

typedef signed char i8;
typedef unsigned long long u64;
typedef signed char c16 __attribute__((ext_vector_type(16)));
typedef int v4i __attribute__((ext_vector_type(4)));

#define NBFM (B_SZ * F_SZ * M_SZ)   // 262144

// ---- workspace layout (bytes) ----
#define OFF_CB    ((size_t)0)          // i8  [F][M][D]      8 MB
#define OFF_CBF   ((size_t)8  << 20)   // i8  frag-linear B  8 MB: [f][dt64][ks8][dsub8][lane64][8]
#define OFF_IN8   ((size_t)16 << 20)   // i8  [B][D]         2 MB
#define OFF_CBBT  ((size_t)18 << 20)   // u64 [F][128][M]    1 MB
#define OFF_INB   ((size_t)19 << 20)   // u64 [B][128]       256 KB
#define OFF_ESB   ((size_t)20 << 20)   // u64 [B][F][128]    1 MB  (sign bits)
#define OFF_EZB   ((size_t)21 << 20)   // u64 [B][F][128]    1 MB  (zero bits)
#define OFF_AF01  ((size_t)22 << 20)   // i8  frag-linear A planes 0,1  512 KB
#define OFF_AF2   (OFF_AF01 + ((size_t)512 << 10))   // i8 frag-linear A plane 2, 256 KB
#define OFF_P1    ((size_t)23 << 20)   // i32 [24][B*F*M]    24 MB  (iter1 partials)
#define OFF_S32   ((size_t)48 << 20)   // i32 [F][D]         128 KB
#define OFF_PDIG  (OFF_S32 + (size_t)F_SZ * D_SZ * 4)   // i8 [3][F][D] 96 KB
#define OFF_CHG   (OFF_PDIG + (size_t)3 * F_SZ * D_SZ)  // int[16]

// frag-linear A slot index for (f, b, m)
__device__ __forceinline__ size_t afslot(int f, int b, int m) {
  return (size_t)(((f * 4 + (b >> 6)) * 8 + (m >> 5)) * 4 + ((b >> 4) & 3)) * 64
         + ((m >> 3) & 3) * 16 + (b & 15);
}

// ---------------- converts / init ----------------

__global__ __launch_bounds__(256) void k_cvt_cb(const float* __restrict__ src,
                                                i8* __restrict__ cb, i8* __restrict__ cbF) {
  __shared__ i8 tile[32][33];   // [m][d]
  const int bid = blockIdx.x;           // 8192 = 4f * 8mt * 256dt
  const int f = bid >> 11;
  const int rem = bid & 2047;
  const int m0 = (rem >> 8) << 5;
  const int d0 = (rem & 255) << 5;
  const int t = threadIdx.x;
  const int i = t >> 3, j = (t & 7) << 2;
  const float4 v = *(const float4*)(src + ((size_t)(f * M_SZ + m0 + i)) * D_SZ + d0 + j);
  char4 c;
  c.x = v.x > 0.f ? 1 : -1;
  c.y = v.y > 0.f ? 1 : -1;
  c.z = v.z > 0.f ? 1 : -1;
  c.w = v.w > 0.f ? 1 : -1;
  *(char4*)(cb + ((size_t)(f * M_SZ + m0 + i)) * D_SZ + d0 + j) = c;
  tile[i][j + 0] = c.x; tile[i][j + 1] = c.y; tile[i][j + 2] = c.z; tile[i][j + 3] = c.w;
  __syncthreads();
  if (t < 128) {
    const int mg = t >> 5;       // 8-m group within the 32-m tile
    const int dd = t & 31;
    const int d = d0 + dd;
    const int dt = d >> 7, dsub = (d >> 4) & 7, dlo = d & 15;
    const int ks = m0 >> 5;
    u64 w = 0;
    #pragma unroll
    for (int jj = 0; jj < 8; ++jj)
      w |= ((u64)(unsigned char)tile[mg * 8 + jj][dd]) << (8 * jj);
    *(u64*)&cbF[((size_t)((((f * 64 + dt) * 8 + ks) * 8 + dsub) * 64 + mg * 16 + dlo)) * 8] = w;
  }
}

__global__ __launch_bounds__(256) void k_cvt_in(const float* __restrict__ src, i8* __restrict__ dst) {
  const int idx = blockIdx.x * 256 + threadIdx.x;   // 524288 float4s
  const float4 v = ((const float4*)src)[idx];
  char4 c;
  c.x = v.x > 0.f ? 1 : -1;
  c.y = v.y > 0.f ? 1 : -1;
  c.z = v.z > 0.f ? 1 : -1;
  c.w = v.w > 0.f ? 1 : -1;
  ((char4*)dst)[idx] = c;
}

__global__ __launch_bounds__(256) void k_pack_cb(const i8* __restrict__ cb, u64* __restrict__ cbbT) {
  const int id = blockIdx.x * 256 + threadIdx.x;   // 131072 = f*32768 + w*256 + m
  const int f = id >> 15;
  const int rem = id & 32767;
  const int w = rem >> 8;
  const int m = rem & 255;
  const i8* src = cb + ((size_t)(f * M_SZ + m)) * D_SZ + w * 64;
  u64 r = 0;
  #pragma unroll
  for (int k = 0; k < 4; ++k) {
    c16 v = *(const c16*)(src + k * 16);
    u64 part = 0;
    #pragma unroll
    for (int j = 0; j < 16; ++j) part |= ((u64)(((unsigned char)v[j]) >> 7)) << j;
    r |= part << (k * 16);
  }
  cbbT[((size_t)(f * 128 + w)) * 256 + m] = r;
}

__global__ __launch_bounds__(256) void k_pack_in(const i8* __restrict__ in8, u64* __restrict__ inb) {
  const int id = blockIdx.x * 256 + threadIdx.x;   // 32768 = b*128 + w
  const int b = id >> 7;
  const int w = id & 127;
  const i8* src = in8 + (size_t)b * D_SZ + w * 64;
  u64 r = 0;
  #pragma unroll
  for (int k = 0; k < 4; ++k) {
    c16 v = *(const c16*)(src + k * 16);
    u64 part = 0;
    #pragma unroll
    for (int j = 0; j < 16; ++j) part |= ((u64)(((unsigned char)v[j]) >> 7)) << j;
    r |= part << (k * 16);
  }
  inb[(size_t)b * 128 + w] = r;
}

__global__ __launch_bounds__(256) void k_S(const i8* __restrict__ cb, int* __restrict__ S) {
  const int id = blockIdx.x * 256 + threadIdx.x;    // 32768 = [f][d]
  const int f = id >> 13, d = id & 8191;
  const i8* p = cb + (size_t)f * M_SZ * D_SZ + d;
  int s = 0;
  for (int m = 0; m < M_SZ; ++m) s += p[(size_t)m * D_SZ];
  S[id] = s;
}

// P' = P/8 (exact), 3 radix-255 signed digits in [-127,127]
__global__ __launch_bounds__(256) void k_P(const int* __restrict__ S, i8* __restrict__ pdig) {
  const int d = blockIdx.x * 256 + threadIdx.x;     // 8192
  const int s0 = S[d], s1 = S[D_SZ + d], s2 = S[2 * D_SZ + d], s3 = S[3 * D_SZ + d];
  int P[4];
  P[0] = s1 * s2 * s3;
  P[1] = s0 * s2 * s3;
  P[2] = s0 * s1 * s3;
  P[3] = s0 * s1 * s2;
  for (int f = 0; f < 4; ++f) {
    int x = P[f] >> 3;
    #pragma unroll
    for (int p = 0; p < 2; ++p) {
      const int y = x + 127;
      const int q = (y >= 0) ? (y / 255) : -((-y + 254) / 255);
      const int dg = x - q * 255;
      pdig[((size_t)(p * F_SZ + f)) * D_SZ + d] = (i8)dg;
      x = q;
    }
    pdig[((size_t)(2 * F_SZ + f)) * D_SZ + d] = (i8)x;
  }
}

// ---------------- iteration-1 stage A (MFMA, 3 digit planes of P/8) ----------------

__global__ __launch_bounds__(256) void ga2_kernel(
    const i8* __restrict__ in8, const i8* __restrict__ cb,
    const i8* __restrict__ pdig, int* __restrict__ p1)
{
  __shared__ __align__(16) i8 lA[64 * 48];
  __shared__ __align__(16) i8 lB[128 * 48];

  const int bid = blockIdx.x;
  const int s = bid & 7;
  const int r = bid >> 3;
  const int p = r % 3;
  const int q = r / 3;
  const int f = q & 3;
  const int ct = q >> 2;
  const int b0 = (ct >> 1) * 64;
  const int m0 = (ct & 1) * 128;
  const int ksteps = 32;
  const int kbase = s << 10;

  const int t = threadIdx.x;
  const int lane = t & 63;
  const int wv = t >> 6;
  const int wrow = (wv >> 1) * 32;
  const int wcol = (wv & 1) * 64;

  const int arow = t >> 1;
  const int aoff = (t & 1) * 16;
  const i8* pB  = cb   + ((size_t)(f * M_SZ + m0 + arow)) * D_SZ + aoff;
  const i8* pDg = pdig + ((size_t)(p * F_SZ + f)) * D_SZ + aoff;
  const i8* pIn = in8  + (size_t)(b0 + arow) * D_SZ + aoff;

  v4i acc[2][4];
  #pragma unroll
  for (int tr = 0; tr < 2; ++tr)
    #pragma unroll
    for (int tc = 0; tc < 4; ++tc) acc[tr][tc] = 0;

  c16 va = 0, vb = 0;
  {
    const int kk = kbase;
    vb = (*(const c16*)(pB + kk)) * (*(const c16*)(pDg + kk));
    if (t < 128) va = *(const c16*)(pIn + kk);
  }

  for (int j = 0; j < ksteps; ++j) {
    c16 sa = va, sb = vb;
    if (j + 1 < ksteps) {
      const int kk = kbase + (j + 1) * 32;
      vb = (*(const c16*)(pB + kk)) * (*(const c16*)(pDg + kk));
      if (t < 128) va = *(const c16*)(pIn + kk);
    }
    __syncthreads();
    if (t < 128) *(c16*)&lA[arow * 48 + aoff] = sa;
    *(c16*)&lB[arow * 48 + aoff] = sb;
    __syncthreads();

    const int rsel = lane & 15;
    const int kq = (lane >> 4) * 8;
    long af[2], bf[4];
    #pragma unroll
    for (int tr = 0; tr < 2; ++tr) af[tr] = *(const long*)&lA[(wrow + tr * 16 + rsel) * 48 + kq];
    #pragma unroll
    for (int tc = 0; tc < 4; ++tc) bf[tc] = *(const long*)&lB[(wcol + tc * 16 + rsel) * 48 + kq];
    #pragma unroll
    for (int tr = 0; tr < 2; ++tr)
      #pragma unroll
      for (int tc = 0; tc < 4; ++tc)
        acc[tr][tc] = __builtin_amdgcn_mfma_i32_16x16x32_i8(af[tr], bf[tc], acc[tr][tc], 0, 0, 0);
  }

  const int colb = lane & 15;
  const int rowq = (lane >> 4) * 4;
  const size_t obase = (size_t)(p * 8 + s) * NBFM;
  #pragma unroll
  for (int tr = 0; tr < 2; ++tr)
    #pragma unroll
    for (int tc = 0; tc < 4; ++tc)
      #pragma unroll
      for (int rr = 0; rr < 4; ++rr) {
        const int b = b0 + wrow + tr * 16 + rowq + rr;
        const int m = m0 + wcol + tc * 16 + colb;
        p1[obase + (((size_t)(b * F_SZ + f)) << 8) + m] = acc[tr][tc][rr];
      }
}

// recombine 24 slices -> 3 radix-256 digits, frag-linear
__global__ __launch_bounds__(256) void k_digits1(const int* __restrict__ p1,
                                                 i8* __restrict__ aF01, i8* __restrict__ aF2) {
  const int idx = blockIdx.x * 256 + threadIdx.x;
  long long g[3];
  #pragma unroll
  for (int p = 0; p < 3; ++p) {
    long long gg = 0;
    #pragma unroll
    for (int s = 0; s < 8; ++s) gg += (long long)p1[(size_t)(p * 8 + s) * NBFM + idx];
    g[p] = gg;
  }
  const long long sim = g[0] + 255LL * g[1] + 65025LL * g[2];
  int x = (int)sim;
  const int r1 = (x + 128) >> 8;
  const int d0 = x - (r1 << 8);
  const int r2 = (r1 + 128) >> 8;
  const int d1 = r1 - (r2 << 8);
  const int bf = idx >> 8;        // b*4+f
  const int m = idx & 255;
  const int b = bf >> 2, f = bf & 3;
  const size_t sl = afslot(f, b, m);
  const int by = m & 7;
  aF01[sl * 16 + by] = (i8)d0;
  aF01[sl * 16 + 8 + by] = (i8)d1;
  aF2[sl * 8 + by] = (i8)r2;
}

// ---------------- gb tile compute (B from LDS; A direct from L2-hot frag-linear global) ----------------

template<int NP, bool FIRST>
__device__ __forceinline__ bool gb_half(
    const i8* bsrc, const i8* aF01, const i8* aF2,
    u64* esb, u64* ezb, const int* S32,
    int f, int bt, int d0, int t)
{
  const int lane = t & 63;
  const int wv = t >> 6;
  const int wrow = (wv >> 1) * 32;
  const int wcol = (wv & 1) * 64;
  const int tb = wcol >> 4;
  const int sub0 = wrow >> 4;
  const int b0 = bt * 64;

  v4i acc[NP][2][4];
  #pragma unroll
  for (int pp = 0; pp < NP; ++pp)
    #pragma unroll
    for (int tr = 0; tr < 2; ++tr)
      #pragma unroll
      for (int tc = 0; tc < 4; ++tc) acc[pp][tr][tc] = 0;

  const i8* pA = aF01 + ((size_t)(f * 4 + bt)) * 32768;
  const i8* pA2 = aF2 + ((size_t)(f * 4 + bt)) * 16384;

  #pragma unroll
  for (int ks = 0; ks < 8; ++ks) {
    long bf[4];
    #pragma unroll
    for (int tc = 0; tc < 4; ++tc)
      bf[tc] = *(const long*)&bsrc[(((ks * 8 + tb + tc) * 64 + lane)) * 8];
    long af[NP][2];
    #pragma unroll
    for (int tr = 0; tr < 2; ++tr) {
      union { c16 v; long l[2]; } x;
      x.v = *(const c16*)(pA + ((size_t)((ks * 4 + sub0 + tr) * 64 + lane)) * 16);
      af[0][tr] = x.l[0];
      af[1][tr] = x.l[1];
      if (NP > 2) af[2][tr] = *(const long*)(pA2 + ((size_t)((ks * 4 + sub0 + tr) * 64 + lane)) * 8);
    }
    #pragma unroll
    for (int pp = 0; pp < NP; ++pp)
      #pragma unroll
      for (int tr = 0; tr < 2; ++tr)
        #pragma unroll
        for (int tc = 0; tc < 4; ++tc)
          acc[pp][tr][tc] = __builtin_amdgcn_mfma_i32_16x16x32_i8(af[pp][tr], bf[tc], acc[pp][tr][tc], 0, 0, 0);
  }

  bool chl = false;
  const int colb = lane & 15;

  #pragma unroll
  for (int tr = 0; tr < 2; ++tr) {
    unsigned long long bs[4][4], bz[4][4];
    #pragma unroll
    for (int rr = 0; rr < 4; ++rr)
      #pragma unroll
      for (int tc = 0; tc < 4; ++tc) {
        int o = acc[0][tr][tc][rr];
        if (NP > 1) o += acc[1][tr][tc][rr] * 256;
        if (NP > 2) o += acc[2][tr][tc][rr] * 65536;
        bs[rr][tc] = __ballot(o < 0);
        bz[rr][tc] = __ballot(o == 0);
        if (FIRST) {
          const int sg = (o > 0) - (o < 0);
          const int d = d0 + wcol + tc * 16 + colb;
          chl |= (sg != S32[f * D_SZ + d]);
        }
      }
    u64 ws = 0, wz = 0;
    #pragma unroll
    for (int rl = 0; rl < 16; ++rl) {
      const int g = rl >> 2, rr = rl & 3;
      u64 vs = 0, vz = 0;
      #pragma unroll
      for (int tc = 0; tc < 4; ++tc) {
        vs |= ((bs[rr][tc] >> (g * 16)) & 0xFFFFull) << (tc * 16);
        vz |= ((bz[rr][tc] >> (g * 16)) & 0xFFFFull) << (tc * 16);
      }
      if (lane == rl) { ws = vs; wz = vz; }
    }
    if (lane < 16) {
      const int row = b0 + wrow + tr * 16 + lane;
      const size_t wi = ((size_t)(row * 4 + f)) * 128 + ((d0 + wcol) >> 6);
      if (!FIRST) chl |= (ws != esb[wi]) | (wz != ezb[wi]);
      esb[wi] = ws;
      ezb[wi] = wz;
    }
  }
  return chl;
}

// ---------------- stage B GEMM kernels, XCD-pinned ----------------
// grid 1024. xcd = bid&7 (HW round-robin): f = xcd>>1, dhalf = xcd&1.
// Each XCD's cbF working set = f-slice x dhalf = 1 MB -> L2-resident across
// all iterations (mapping identical every dispatch).

template<int NP, bool FIRST>
__device__ __forceinline__ void gb_body(
    const i8* __restrict__ aF01, const i8* __restrict__ aF2,
    const i8* __restrict__ cbF,
    u64* __restrict__ esb, u64* __restrict__ ezb,
    const int* __restrict__ S32,
    int* __restrict__ changed, int it)
{
  __shared__ __align__(16) i8 lB[32768];

  if (!FIRST) { if (changed[it - 1] == 0) return; }

  const int bid = blockIdx.x;
  const int xcd = bid & 7;
  const int f = xcd >> 1;
  const int r = bid >> 3;            // 0..127
  const int bt = r & 3;
  const int dt = (xcd & 1) * 32 + (r >> 2);   // 0..63

  const int t = threadIdx.x;
  {
    const i8* src = cbF + ((size_t)(f * 64 + dt)) * 32768;
    #pragma unroll
    for (int i = 0; i < 8; ++i) {
      const int off = i * 4096 + t * 16;
      *(c16*)&lB[off] = *(const c16*)(src + off);
    }
  }
  __syncthreads();

  bool chl = gb_half<NP, FIRST>(lB, aF01, aF2, esb, ezb, S32, f, bt, dt * 128, t);
  if (__any(chl)) { if ((t & 63) == 0) atomicOr(&changed[it], 1); }
}

__global__ __launch_bounds__(256, 4) void gb_loop_k(
    const i8* __restrict__ aF01, const i8* __restrict__ cbF,
    u64* __restrict__ esb, u64* __restrict__ ezb,
    int* __restrict__ changed, int it)
{
  gb_body<2, false>(aF01, nullptr, cbF, esb, ezb, nullptr, changed, it);
}

__global__ __launch_bounds__(256, 2) void gb_first_k(
    const i8* __restrict__ aF01, const i8* __restrict__ aF2, const i8* __restrict__ cbF,
    u64* __restrict__ esb, u64* __restrict__ ezb,
    const int* __restrict__ S32, int* __restrict__ changed, int it)
{
  gb_body<3, true>(aF01, aF2, cbF, esb, ezb, S32, changed, it);
}

// ---------------- bitwise stage A (iters >= 2), XCD-pinned ----------------
// grid 512 x 512 threads. xcd = bid&7: f = xcd>>1 -> cbbT f-slice (256 KB) L2-resident/XCD.
// rows pair = (xcd&1)*64 + (bid>>3).

__global__ __launch_bounds__(512) void ga_bit(
    const u64* __restrict__ esb, const u64* __restrict__ ezb,
    const u64* __restrict__ inb, const u64* __restrict__ cbbT,
    i8* __restrict__ aF01, const int* __restrict__ changed, int it)
{
  __shared__ u64 AL[128][4];

  if (changed[it - 1] == 0) return;

  const int bid = blockIdx.x;
  const int xcd = bid & 7;
  const int f = xcd >> 1;
  const int b0 = ((xcd & 1) * 64 + (bid >> 3)) * 2;
  const int t = threadIdx.x;

  if (t < 256) {
    const int r = t >> 7, w = t & 127;
    const int b = b0 + r;
    int ffs[3]; int c = 0;
    for (int ff = 0; ff < 4; ++ff) if (ff != f) ffs[c++] = ff;
    const size_t base = (size_t)b * 512;
    const u64 s = inb[(size_t)b * 128 + w]
      ^ esb[base + ffs[0] * 128 + w] ^ esb[base + ffs[1] * 128 + w] ^ esb[base + ffs[2] * 128 + w];
    const u64 nz = ~(ezb[base + ffs[0] * 128 + w] | ezb[base + ffs[1] * 128 + w] | ezb[base + ffs[2] * 128 + w]);
    AL[w][r * 2] = s;
    AL[w][r * 2 + 1] = nz;
  }
  __syncthreads();

  const int r = t >> 8;
  const int m = t & 255;
  int a = 0, c = 0;
  const u64* pc = cbbT + (size_t)f * 32768 + m;
  #pragma unroll 4
  for (int w = 0; w < 128; ++w) {
    const u64 cbw = pc[w * 256];
    a += (int)__popcll((AL[w][r * 2] ^ cbw) & AL[w][r * 2 + 1]);
    c += (int)__popcll(AL[w][r * 2 + 1]);
  }
  const int sim = c - 2 * a;

  const int d1 = (sim + 128) >> 8;
  const int d0v = sim - (d1 << 8);
  const int b = b0 + r;
  const size_t sl = afslot(f, b, m);
  const int by = m & 7;
  aF01[sl * 16 + by] = (i8)d0v;
  aF01[sl * 16 + 8 + by] = (i8)d1;
}

// ---------------- final: sim + argmax + k, XCD-pinned ----------------

__global__ __launch_bounds__(512) void k_final(
    const u64* __restrict__ esb, const u64* __restrict__ ezb,
    const u64* __restrict__ cbbT, const int* __restrict__ chg,
    int* __restrict__ out)
{
  __shared__ u64 AL[128][4];
  __shared__ long long red[2][256];

  const int bid = blockIdx.x;
  const int xcd = bid & 7;
  const int f = xcd >> 1;
  const int b0 = ((xcd & 1) * 64 + (bid >> 3)) * 2;
  const int t = threadIdx.x;

  if (t < 256) {
    const int r = t >> 7, w = t & 127;
    const int b = b0 + r;
    const size_t a = ((size_t)b * 4 + f) * 128 + w;
    AL[w][r * 2] = esb[a];
    AL[w][r * 2 + 1] = ~ezb[a];
  }
  __syncthreads();

  const int r = t >> 8;
  const int m = t & 255;
  int a = 0, c = 0;
  const u64* pc = cbbT + (size_t)f * 32768 + m;
  #pragma unroll 4
  for (int w = 0; w < 128; ++w) {
    const u64 cbw = pc[w * 256];
    a += (int)__popcll((AL[w][r * 2] ^ cbw) & AL[w][r * 2 + 1]);
    c += (int)__popcll(AL[w][r * 2 + 1]);
  }
  const int sim = c - 2 * a;

  red[r][m] = ((long long)sim << 32) | (long long)(unsigned)(255 - m);
  __syncthreads();
  for (int s2 = 128; s2 > 0; s2 >>= 1) {
    if (m < s2) {
      if (red[r][m + s2] > red[r][m]) red[r][m] = red[r][m + s2];
    }
    __syncthreads();
  }
  if (m == 0) {
    out[(b0 + r) * 4 + f] = 255 - (int)(red[r][0] & 0xFFFF);
    if (t == 0 && bid == 0) {
      int k = NITER;
      for (int i = 1; i <= NITER; ++i) if (chg[i] == 0) { k = i; break; }
      out[B_SZ * F_SZ] = k;
    }
  }
}

// ---------------- host ----------------

extern "C" void kernel_launch(void* const* d_in, const int* in_sizes, int n_in,
                              void* d_out, int out_size, void* d_ws, size_t ws_size,
                              hipStream_t stream) {
  const float* f_in = (const float*)d_in[0];   // [B][D]
  const float* f_cb = (const float*)d_in[1];   // [F][M][D]
  int* out = (int*)d_out;
  char* ws = (char*)d_ws;

  i8*  cb8  = (i8*)(ws + OFF_CB);
  i8*  cbF  = (i8*)(ws + OFF_CBF);
  i8*  in8  = (i8*)(ws + OFF_IN8);
  u64* cbbT = (u64*)(ws + OFF_CBBT);
  u64* inb  = (u64*)(ws + OFF_INB);
  u64* esb  = (u64*)(ws + OFF_ESB);
  u64* ezb  = (u64*)(ws + OFF_EZB);
  i8*  aF01 = (i8*)(ws + OFF_AF01);
  i8*  aF2  = (i8*)(ws + OFF_AF2);
  int* p1   = (int*)(ws + OFF_P1);
  int* S32  = (int*)(ws + OFF_S32);
  i8*  pdig = (i8*)(ws + OFF_PDIG);
  int* chg  = (int*)(ws + OFF_CHG);

  hipMemsetAsync(chg, 0, 64, stream);
  k_cvt_cb<<<dim3(8192), dim3(256), 0, stream>>>(f_cb, cb8, cbF);
  k_cvt_in<<<dim3(2048), dim3(256), 0, stream>>>(f_in, in8);
  k_pack_cb<<<dim3(512), dim3(256), 0, stream>>>(cb8, cbbT);
  k_pack_in<<<dim3(128), dim3(256), 0, stream>>>(in8, inb);
  k_S<<<dim3(128), dim3(256), 0, stream>>>(cb8, S32);
  k_P<<<dim3(32), dim3(256), 0, stream>>>(S32, pdig);

  // iteration 1 stage A (big-integer est0 via P/8 digit planes, MFMA)
  ga2_kernel<<<dim3(768), dim3(256), 0, stream>>>(in8, cb8, pdig, p1);
  k_digits1<<<dim3(1024), dim3(256), 0, stream>>>(p1, aF01, aF2);
  gb_first_k<<<dim3(1024), dim3(256), 0, stream>>>(aF01, aF2, cbF, esb, ezb, S32, chg, 1);

  for (int it = 2; it <= NITER; ++it) {
    ga_bit<<<dim3(512), dim3(512), 0, stream>>>(esb, ezb, inb, cbbT, aF01, chg, it);
    gb_loop_k<<<dim3(1024), dim3(256), 0, stream>>>(aF01, cbF, esb, ezb, chg, it);
  }

  // final sim + argmax + k
  k_final<<<dim3(512), dim3(512), 0, stream>>>(esb, ezb, cbbT, chg, out);
}

// Round 7
// 855.190 us; speedup vs baseline: 1.9361x; 1.0245x over previous
//
#include <hip/hip_runtime.h>

#define B_SZ 256
#define F_SZ 4
#define M_SZ 256
#define D_SZ 8192
#define NITER 10

typedef signed char i8;
typedef unsigned long long u64;
typedef signed char c16 __attribute__((ext_vector_type(16)));
typedef int v4i __attribute__((ext_vector_type(4)));

#define NBFM (B_SZ * F_SZ * M_SZ)   // 262144

// ---- workspace layout (bytes) ----
#define OFF_CB    ((size_t)0)          // i8  [F][M][D]      8 MB
#define OFF_CBFB  ((size_t)8  << 20)   // u8  PACKED frag-linear B 1 MB: [(f*64+dt)*4096 + (ks*8+dsub)*64 + mg*16 + dlo]
#define OFF_IN8   ((size_t)16 << 20)   // i8  [B][D]         2 MB
#define OFF_CBBT  ((size_t)18 << 20)   // u64 [F][128][M]    1 MB
#define OFF_INB   ((size_t)19 << 20)   // u64 [B][128]       256 KB
#define OFF_ESB   ((size_t)20 << 20)   // u64 [B][F][128]    1 MB  (sign bits)
#define OFF_EZB   ((size_t)21 << 20)   // u64 [B][F][128]    1 MB  (zero bits)
#define OFF_AF01  ((size_t)22 << 20)   // i8  frag-linear A planes 0,1  512 KB
#define OFF_AF2   (OFF_AF01 + ((size_t)512 << 10))   // i8 frag-linear A plane 2, 256 KB
#define OFF_P1    ((size_t)23 << 20)   // i32 [24][B*F*M]    24 MB  (iter1 partials)
#define OFF_S32   ((size_t)48 << 20)   // i32 [F][D]         128 KB
#define OFF_PDIG  (OFF_S32 + (size_t)F_SZ * D_SZ * 4)   // i8 [3][F][D] 96 KB
#define OFF_CHG   (OFF_PDIG + (size_t)3 * F_SZ * D_SZ)  // int[16]

// frag-linear A slot index for (f, b, m)
__device__ __forceinline__ size_t afslot(int f, int b, int m) {
  return (size_t)(((f * 4 + (b >> 6)) * 8 + (m >> 5)) * 4 + ((b >> 4) & 3)) * 64
         + ((m >> 3) & 3) * 16 + (b & 15);
}

// expand 8 packed sign bits (bit=1 => -1) to 8 i8 bytes {+1,-1}
__device__ __forceinline__ long expand_pm1(unsigned b) {
  u64 x = (u64)b * 0x0101010101010101ULL;   // replicate byte
  x &= 0x8040201008040201ULL;               // byte i holds bit i (as 1<<i)
  x += 0x00406070787C7E7FULL;               // byte i: nonzero -> bit7 set
  x &= 0x8080808080808080ULL;
  u64 s = x >> 7;                           // 0x01 per set byte
  return (long)(0x0101010101010101ULL ^ (s * 0xFEULL));   // set->0xFF(-1), clear->0x01
}

// ---------------- converts / init ----------------

// cb8 [f][m][d] signs + cbFb packed frag-linear B bits
__global__ __launch_bounds__(256) void k_cvt_cb(const float* __restrict__ src,
                                                i8* __restrict__ cb, unsigned char* __restrict__ cbFb) {
  __shared__ i8 tile[32][33];   // [m][d]
  const int bid = blockIdx.x;           // 8192 = 4f * 8mt * 256dt
  const int f = bid >> 11;
  const int rem = bid & 2047;
  const int m0 = (rem >> 8) << 5;
  const int d0 = (rem & 255) << 5;
  const int t = threadIdx.x;
  const int i = t >> 3, j = (t & 7) << 2;
  const float4 v = *(const float4*)(src + ((size_t)(f * M_SZ + m0 + i)) * D_SZ + d0 + j);
  char4 c;
  c.x = v.x > 0.f ? 1 : -1;
  c.y = v.y > 0.f ? 1 : -1;
  c.z = v.z > 0.f ? 1 : -1;
  c.w = v.w > 0.f ? 1 : -1;
  *(char4*)(cb + ((size_t)(f * M_SZ + m0 + i)) * D_SZ + d0 + j) = c;
  tile[i][j + 0] = c.x; tile[i][j + 1] = c.y; tile[i][j + 2] = c.z; tile[i][j + 3] = c.w;
  __syncthreads();
  if (t < 128) {
    const int mg = t >> 5;       // m-octet within the 32-m tile (= within ks)
    const int dd = t & 31;
    const int d = d0 + dd;
    const int dt = d >> 7, dsub = (d >> 4) & 7, dlo = d & 15;
    const int ks = m0 >> 5;
    unsigned pk = 0;
    #pragma unroll
    for (int jj = 0; jj < 8; ++jj)
      pk |= ((((unsigned char)tile[mg * 8 + jj][dd]) >> 7) & 1u) << jj;
    cbFb[(size_t)(f * 64 + dt) * 4096 + (ks * 8 + dsub) * 64 + mg * 16 + dlo] = (unsigned char)pk;
  }
}

__global__ __launch_bounds__(256) void k_cvt_in(const float* __restrict__ src, i8* __restrict__ dst) {
  const int idx = blockIdx.x * 256 + threadIdx.x;   // 524288 float4s
  const float4 v = ((const float4*)src)[idx];
  char4 c;
  c.x = v.x > 0.f ? 1 : -1;
  c.y = v.y > 0.f ? 1 : -1;
  c.z = v.z > 0.f ? 1 : -1;
  c.w = v.w > 0.f ? 1 : -1;
  ((char4*)dst)[idx] = c;
}

__global__ __launch_bounds__(256) void k_pack_cb(const i8* __restrict__ cb, u64* __restrict__ cbbT) {
  const int id = blockIdx.x * 256 + threadIdx.x;   // 131072 = f*32768 + w*256 + m
  const int f = id >> 15;
  const int rem = id & 32767;
  const int w = rem >> 8;
  const int m = rem & 255;
  const i8* src = cb + ((size_t)(f * M_SZ + m)) * D_SZ + w * 64;
  u64 r = 0;
  #pragma unroll
  for (int k = 0; k < 4; ++k) {
    c16 v = *(const c16*)(src + k * 16);
    u64 part = 0;
    #pragma unroll
    for (int j = 0; j < 16; ++j) part |= ((u64)(((unsigned char)v[j]) >> 7)) << j;
    r |= part << (k * 16);
  }
  cbbT[((size_t)(f * 128 + w)) * 256 + m] = r;
}

__global__ __launch_bounds__(256) void k_pack_in(const i8* __restrict__ in8, u64* __restrict__ inb) {
  const int id = blockIdx.x * 256 + threadIdx.x;   // 32768 = b*128 + w
  const int b = id >> 7;
  const int w = id & 127;
  const i8* src = in8 + (size_t)b * D_SZ + w * 64;
  u64 r = 0;
  #pragma unroll
  for (int k = 0; k < 4; ++k) {
    c16 v = *(const c16*)(src + k * 16);
    u64 part = 0;
    #pragma unroll
    for (int j = 0; j < 16; ++j) part |= ((u64)(((unsigned char)v[j]) >> 7)) << j;
    r |= part << (k * 16);
  }
  inb[(size_t)b * 128 + w] = r;
}

__global__ __launch_bounds__(256) void k_S(const i8* __restrict__ cb, int* __restrict__ S) {
  const int id = blockIdx.x * 256 + threadIdx.x;    // 32768 = [f][d]
  const int f = id >> 13, d = id & 8191;
  const i8* p = cb + (size_t)f * M_SZ * D_SZ + d;
  int s = 0;
  for (int m = 0; m < M_SZ; ++m) s += p[(size_t)m * D_SZ];
  S[id] = s;
}

// P' = P/8 (exact), 3 radix-255 signed digits in [-127,127]
__global__ __launch_bounds__(256) void k_P(const int* __restrict__ S, i8* __restrict__ pdig) {
  const int d = blockIdx.x * 256 + threadIdx.x;     // 8192
  const int s0 = S[d], s1 = S[D_SZ + d], s2 = S[2 * D_SZ + d], s3 = S[3 * D_SZ + d];
  int P[4];
  P[0] = s1 * s2 * s3;
  P[1] = s0 * s2 * s3;
  P[2] = s0 * s1 * s3;
  P[3] = s0 * s1 * s2;
  for (int f = 0; f < 4; ++f) {
    int x = P[f] >> 3;
    #pragma unroll
    for (int p = 0; p < 2; ++p) {
      const int y = x + 127;
      const int q = (y >= 0) ? (y / 255) : -((-y + 254) / 255);
      const int dg = x - q * 255;
      pdig[((size_t)(p * F_SZ + f)) * D_SZ + d] = (i8)dg;
      x = q;
    }
    pdig[((size_t)(2 * F_SZ + f)) * D_SZ + d] = (i8)x;
  }
}

// ---------------- iteration-1 stage A (MFMA, 3 digit planes of P/8) ----------------

__global__ __launch_bounds__(256) void ga2_kernel(
    const i8* __restrict__ in8, const i8* __restrict__ cb,
    const i8* __restrict__ pdig, int* __restrict__ p1)
{
  __shared__ __align__(16) i8 lA[64 * 48];
  __shared__ __align__(16) i8 lB[128 * 48];

  const int bid = blockIdx.x;
  const int s = bid & 7;
  const int r = bid >> 3;
  const int p = r % 3;
  const int q = r / 3;
  const int f = q & 3;
  const int ct = q >> 2;
  const int b0 = (ct >> 1) * 64;
  const int m0 = (ct & 1) * 128;
  const int ksteps = 32;
  const int kbase = s << 10;

  const int t = threadIdx.x;
  const int lane = t & 63;
  const int wv = t >> 6;
  const int wrow = (wv >> 1) * 32;
  const int wcol = (wv & 1) * 64;

  const int arow = t >> 1;
  const int aoff = (t & 1) * 16;
  const i8* pB  = cb   + ((size_t)(f * M_SZ + m0 + arow)) * D_SZ + aoff;
  const i8* pDg = pdig + ((size_t)(p * F_SZ + f)) * D_SZ + aoff;
  const i8* pIn = in8  + (size_t)(b0 + arow) * D_SZ + aoff;

  v4i acc[2][4];
  #pragma unroll
  for (int tr = 0; tr < 2; ++tr)
    #pragma unroll
    for (int tc = 0; tc < 4; ++tc) acc[tr][tc] = 0;

  c16 va = 0, vb = 0;
  {
    const int kk = kbase;
    vb = (*(const c16*)(pB + kk)) * (*(const c16*)(pDg + kk));
    if (t < 128) va = *(const c16*)(pIn + kk);
  }

  for (int j = 0; j < ksteps; ++j) {
    c16 sa = va, sb = vb;
    if (j + 1 < ksteps) {
      const int kk = kbase + (j + 1) * 32;
      vb = (*(const c16*)(pB + kk)) * (*(const c16*)(pDg + kk));
      if (t < 128) va = *(const c16*)(pIn + kk);
    }
    __syncthreads();
    if (t < 128) *(c16*)&lA[arow * 48 + aoff] = sa;
    *(c16*)&lB[arow * 48 + aoff] = sb;
    __syncthreads();

    const int rsel = lane & 15;
    const int kq = (lane >> 4) * 8;
    long af[2], bf[4];
    #pragma unroll
    for (int tr = 0; tr < 2; ++tr) af[tr] = *(const long*)&lA[(wrow + tr * 16 + rsel) * 48 + kq];
    #pragma unroll
    for (int tc = 0; tc < 4; ++tc) bf[tc] = *(const long*)&lB[(wcol + tc * 16 + rsel) * 48 + kq];
    #pragma unroll
    for (int tr = 0; tr < 2; ++tr)
      #pragma unroll
      for (int tc = 0; tc < 4; ++tc)
        acc[tr][tc] = __builtin_amdgcn_mfma_i32_16x16x32_i8(af[tr], bf[tc], acc[tr][tc], 0, 0, 0);
  }

  const int colb = lane & 15;
  const int rowq = (lane >> 4) * 4;
  const size_t obase = (size_t)(p * 8 + s) * NBFM;
  #pragma unroll
  for (int tr = 0; tr < 2; ++tr)
    #pragma unroll
    for (int tc = 0; tc < 4; ++tc)
      #pragma unroll
      for (int rr = 0; rr < 4; ++rr) {
        const int b = b0 + wrow + tr * 16 + rowq + rr;
        const int m = m0 + wcol + tc * 16 + colb;
        p1[obase + (((size_t)(b * F_SZ + f)) << 8) + m] = acc[tr][tc][rr];
      }
}

// recombine 24 slices -> 3 radix-256 digits, frag-linear
__global__ __launch_bounds__(256) void k_digits1(const int* __restrict__ p1,
                                                 i8* __restrict__ aF01, i8* __restrict__ aF2) {
  const int idx = blockIdx.x * 256 + threadIdx.x;
  long long g[3];
  #pragma unroll
  for (int p = 0; p < 3; ++p) {
    long long gg = 0;
    #pragma unroll
    for (int s = 0; s < 8; ++s) gg += (long long)p1[(size_t)(p * 8 + s) * NBFM + idx];
    g[p] = gg;
  }
  const long long sim = g[0] + 255LL * g[1] + 65025LL * g[2];
  int x = (int)sim;
  const int r1 = (x + 128) >> 8;
  const int d0 = x - (r1 << 8);
  const int r2 = (r1 + 128) >> 8;
  const int d1 = r1 - (r2 << 8);
  const int bf = idx >> 8;        // b*4+f
  const int m = idx & 255;
  const int b = bf >> 2, f = bf & 3;
  const size_t sl = afslot(f, b, m);
  const int by = m & 7;
  aF01[sl * 16 + by] = (i8)d0;
  aF01[sl * 16 + 8 + by] = (i8)d1;
  aF2[sl * 8 + by] = (i8)r2;
}

// ---------------- stage B GEMM: packed-bit B expanded in registers, no LDS, no barriers ----------------
// grid 1024: xcd-ish decode kept from r6 (harmless). B-source = 1 MB packed -> L2-resident everywhere.

template<int NP, bool FIRST>
__device__ __forceinline__ void gb_body(
    const i8* __restrict__ aF01, const i8* __restrict__ aF2,
    const unsigned char* __restrict__ cbFb,
    u64* __restrict__ esb, u64* __restrict__ ezb,
    const int* __restrict__ S32,
    int* __restrict__ changed, int it)
{
  if (!FIRST) { if (changed[it - 1] == 0) return; }

  const int bid = blockIdx.x;
  const int xcd = bid & 7;
  const int f = xcd >> 1;
  const int r = bid >> 3;            // 0..127
  const int bt = r & 3;
  const int dt = (xcd & 1) * 32 + (r >> 2);   // 0..63
  const int d0 = dt * 128;

  const int t = threadIdx.x;
  const int lane = t & 63;
  const int wv = t >> 6;
  const int wrow = (wv >> 1) * 32;
  const int wcol = (wv & 1) * 64;
  const int tb = wcol >> 4;        // 0 or 4
  const int sub0 = wrow >> 4;      // 0 or 2
  const int b0 = bt * 64;

  v4i acc[NP][2][4];
  #pragma unroll
  for (int pp = 0; pp < NP; ++pp)
    #pragma unroll
    for (int tr = 0; tr < 2; ++tr)
      #pragma unroll
      for (int tc = 0; tc < 4; ++tc) acc[pp][tr][tc] = 0;

  const i8* pA = aF01 + ((size_t)(f * 4 + bt)) * 32768;
  const i8* pA2 = aF2 + ((size_t)(f * 4 + bt)) * 16384;
  const unsigned char* pb = cbFb + (size_t)(f * 64 + dt) * 4096 + tb * 64 + lane;

  #pragma unroll
  for (int ks = 0; ks < 8; ++ks) {
    long bf[4];
    #pragma unroll
    for (int tc = 0; tc < 4; ++tc)
      bf[tc] = expand_pm1(pb[ks * 512 + tc * 64]);
    long af[NP][2];
    #pragma unroll
    for (int tr = 0; tr < 2; ++tr) {
      union { c16 v; long l[2]; } x;
      x.v = *(const c16*)(pA + ((size_t)((ks * 4 + sub0 + tr) * 64 + lane)) * 16);
      af[0][tr] = x.l[0];
      af[1][tr] = x.l[1];
      if (NP > 2) af[2][tr] = *(const long*)(pA2 + ((size_t)((ks * 4 + sub0 + tr) * 64 + lane)) * 8);
    }
    #pragma unroll
    for (int pp = 0; pp < NP; ++pp)
      #pragma unroll
      for (int tr = 0; tr < 2; ++tr)
        #pragma unroll
        for (int tc = 0; tc < 4; ++tc)
          acc[pp][tr][tc] = __builtin_amdgcn_mfma_i32_16x16x32_i8(af[pp][tr], bf[tc], acc[pp][tr][tc], 0, 0, 0);
  }

  bool chl = false;
  const int colb = lane & 15;

  #pragma unroll
  for (int tr = 0; tr < 2; ++tr) {
    unsigned long long bs[4][4], bz[4][4];
    #pragma unroll
    for (int rr = 0; rr < 4; ++rr)
      #pragma unroll
      for (int tc = 0; tc < 4; ++tc) {
        int o = acc[0][tr][tc][rr];
        if (NP > 1) o += acc[1][tr][tc][rr] * 256;
        if (NP > 2) o += acc[2][tr][tc][rr] * 65536;
        bs[rr][tc] = __ballot(o < 0);
        bz[rr][tc] = __ballot(o == 0);
        if (FIRST) {
          const int sg = (o > 0) - (o < 0);
          const int d = d0 + wcol + tc * 16 + colb;
          chl |= (sg != S32[f * D_SZ + d]);
        }
      }
    u64 ws = 0, wz = 0;
    #pragma unroll
    for (int rl = 0; rl < 16; ++rl) {
      const int g = rl >> 2, rr = rl & 3;
      u64 vs = 0, vz = 0;
      #pragma unroll
      for (int tc = 0; tc < 4; ++tc) {
        vs |= ((bs[rr][tc] >> (g * 16)) & 0xFFFFull) << (tc * 16);
        vz |= ((bz[rr][tc] >> (g * 16)) & 0xFFFFull) << (tc * 16);
      }
      if (lane == rl) { ws = vs; wz = vz; }
    }
    if (lane < 16) {
      const int row = b0 + wrow + tr * 16 + lane;
      const size_t wi = ((size_t)(row * 4 + f)) * 128 + ((d0 + wcol) >> 6);
      if (!FIRST) chl |= (ws != esb[wi]) | (wz != ezb[wi]);
      esb[wi] = ws;
      ezb[wi] = wz;
    }
  }
  if (__any(chl)) { if (lane == 0) atomicOr(&changed[it], 1); }
}

__global__ __launch_bounds__(256, 4) void gb_loop_k(
    const i8* __restrict__ aF01, const unsigned char* __restrict__ cbFb,
    u64* __restrict__ esb, u64* __restrict__ ezb,
    int* __restrict__ changed, int it)
{
  gb_body<2, false>(aF01, nullptr, cbFb, esb, ezb, nullptr, changed, it);
}

__global__ __launch_bounds__(256, 3) void gb_first_k(
    const i8* __restrict__ aF01, const i8* __restrict__ aF2, const unsigned char* __restrict__ cbFb,
    u64* __restrict__ esb, u64* __restrict__ ezb,
    const int* __restrict__ S32, int* __restrict__ changed, int it)
{
  gb_body<3, true>(aF01, aF2, cbFb, esb, ezb, S32, changed, it);
}

// ---------------- bitwise stage A (iters >= 2) ----------------

__global__ __launch_bounds__(512) void ga_bit(
    const u64* __restrict__ esb, const u64* __restrict__ ezb,
    const u64* __restrict__ inb, const u64* __restrict__ cbbT,
    i8* __restrict__ aF01, const int* __restrict__ changed, int it)
{
  __shared__ u64 AL[128][4];

  if (changed[it - 1] == 0) return;

  const int bid = blockIdx.x;
  const int xcd = bid & 7;
  const int f = xcd >> 1;
  const int b0 = ((xcd & 1) * 64 + (bid >> 3)) * 2;
  const int t = threadIdx.x;

  if (t < 256) {
    const int r = t >> 7, w = t & 127;
    const int b = b0 + r;
    int ffs[3]; int c = 0;
    for (int ff = 0; ff < 4; ++ff) if (ff != f) ffs[c++] = ff;
    const size_t base = (size_t)b * 512;
    const u64 s = inb[(size_t)b * 128 + w]
      ^ esb[base + ffs[0] * 128 + w] ^ esb[base + ffs[1] * 128 + w] ^ esb[base + ffs[2] * 128 + w];
    const u64 nz = ~(ezb[base + ffs[0] * 128 + w] | ezb[base + ffs[1] * 128 + w] | ezb[base + ffs[2] * 128 + w]);
    AL[w][r * 2] = s;
    AL[w][r * 2 + 1] = nz;
  }
  __syncthreads();

  const int r = t >> 8;
  const int m = t & 255;
  int a = 0, c = 0;
  const u64* pc = cbbT + (size_t)f * 32768 + m;
  #pragma unroll 8
  for (int w = 0; w < 128; ++w) {
    const u64 cbw = pc[w * 256];
    a += (int)__popcll((AL[w][r * 2] ^ cbw) & AL[w][r * 2 + 1]);
    c += (int)__popcll(AL[w][r * 2 + 1]);
  }
  const int sim = c - 2 * a;

  const int d1 = (sim + 128) >> 8;
  const int d0v = sim - (d1 << 8);
  const int b = b0 + r;
  const size_t sl = afslot(f, b, m);
  const int by = m & 7;
  aF01[sl * 16 + by] = (i8)d0v;
  aF01[sl * 16 + 8 + by] = (i8)d1;
}

// ---------------- final: sim + argmax + k ----------------

__global__ __launch_bounds__(512) void k_final(
    const u64* __restrict__ esb, const u64* __restrict__ ezb,
    const u64* __restrict__ cbbT, const int* __restrict__ chg,
    int* __restrict__ out)
{
  __shared__ u64 AL[128][4];
  __shared__ long long red[2][256];

  const int bid = blockIdx.x;
  const int xcd = bid & 7;
  const int f = xcd >> 1;
  const int b0 = ((xcd & 1) * 64 + (bid >> 3)) * 2;
  const int t = threadIdx.x;

  if (t < 256) {
    const int r = t >> 7, w = t & 127;
    const int b = b0 + r;
    const size_t a = ((size_t)b * 4 + f) * 128 + w;
    AL[w][r * 2] = esb[a];
    AL[w][r * 2 + 1] = ~ezb[a];
  }
  __syncthreads();

  const int r = t >> 8;
  const int m = t & 255;
  int a = 0, c = 0;
  const u64* pc = cbbT + (size_t)f * 32768 + m;
  #pragma unroll 8
  for (int w = 0; w < 128; ++w) {
    const u64 cbw = pc[w * 256];
    a += (int)__popcll((AL[w][r * 2] ^ cbw) & AL[w][r * 2 + 1]);
    c += (int)__popcll(AL[w][r * 2 + 1]);
  }
  const int sim = c - 2 * a;

  red[r][m] = ((long long)sim << 32) | (long long)(unsigned)(255 - m);
  __syncthreads();
  for (int s2 = 128; s2 > 0; s2 >>= 1) {
    if (m < s2) {
      if (red[r][m + s2] > red[r][m]) red[r][m] = red[r][m + s2];
    }
    __syncthreads();
  }
  if (m == 0) {
    out[(b0 + r) * 4 + f] = 255 - (int)(red[r][0] & 0xFFFF);
    if (t == 0 && bid == 0) {
      int k = NITER;
      for (int i = 1; i <= NITER; ++i) if (chg[i] == 0) { k = i; break; }
      out[B_SZ * F_SZ] = k;
    }
  }
}

// ---------------- host ----------------

extern "C" void kernel_launch(void* const* d_in, const int* in_sizes, int n_in,
                              void* d_out, int out_size, void* d_ws, size_t ws_size,
                              hipStream_t stream) {
  const float* f_in = (const float*)d_in[0];   // [B][D]
  const float* f_cb = (const float*)d_in[1];   // [F][M][D]
  int* out = (int*)d_out;
  char* ws = (char*)d_ws;

  i8*  cb8  = (i8*)(ws + OFF_CB);
  unsigned char* cbFb = (unsigned char*)(ws + OFF_CBFB);
  i8*  in8  = (i8*)(ws + OFF_IN8);
  u64* cbbT = (u64*)(ws + OFF_CBBT);
  u64* inb  = (u64*)(ws + OFF_INB);
  u64* esb  = (u64*)(ws + OFF_ESB);
  u64* ezb  = (u64*)(ws + OFF_EZB);
  i8*  aF01 = (i8*)(ws + OFF_AF01);
  i8*  aF2  = (i8*)(ws + OFF_AF2);
  int* p1   = (int*)(ws + OFF_P1);
  int* S32  = (int*)(ws + OFF_S32);
  i8*  pdig = (i8*)(ws + OFF_PDIG);
  int* chg  = (int*)(ws + OFF_CHG);

  hipMemsetAsync(chg, 0, 64, stream);
  k_cvt_cb<<<dim3(8192), dim3(256), 0, stream>>>(f_cb, cb8, cbFb);
  k_cvt_in<<<dim3(2048), dim3(256), 0, stream>>>(f_in, in8);
  k_pack_cb<<<dim3(512), dim3(256), 0, stream>>>(cb8, cbbT);
  k_pack_in<<<dim3(128), dim3(256), 0, stream>>>(in8, inb);
  k_S<<<dim3(128), dim3(256), 0, stream>>>(cb8, S32);
  k_P<<<dim3(32), dim3(256), 0, stream>>>(S32, pdig);

  // iteration 1 stage A (big-integer est0 via P/8 digit planes, MFMA)
  ga2_kernel<<<dim3(768), dim3(256), 0, stream>>>(in8, cb8, pdig, p1);
  k_digits1<<<dim3(1024), dim3(256), 0, stream>>>(p1, aF01, aF2);
  gb_first_k<<<dim3(1024), dim3(256), 0, stream>>>(aF01, aF2, cbFb, esb, ezb, S32, chg, 1);

  for (int it = 2; it <= NITER; ++it) {
    ga_bit<<<dim3(512), dim3(512), 0, stream>>>(esb, ezb, inb, cbbT, aF01, chg, it);
    gb_loop_k<<<dim3(1024), dim3(256), 0, stream>>>(aF01, cbFb, esb, ezb, chg, it);
  }

  // final sim + argmax + k
  k_final<<<dim3(512), dim3(512), 0, stream>>>(esb, ezb, cbbT, chg, out);
}